// Round 2
// baseline (216.342 us; speedup 1.0000x reference)
//
#include <hip/hip_runtime.h>

// Problem constants: B=32, T=512, F=513, S=3
#define BB 32
#define NN (512 * 513)                 // 262656 elements per (b, source)
#define FLOATS_PER_B (NN * 3)          // 787968 floats per batch slice
#define F4_PER_B (FLOATS_PER_B / 4)    // 196992 float4 per batch slice
// 65664 chunks-of-12 per b = 513 tiles x 128 chunks
#define THREADS 128
#define TILE_F4 384                    // 128 chunks * 3 float4
#define TILES_PER_B 513
#define TILES_PER_BLOCK 3
#define BLOCKS_PER_B (TILES_PER_B / TILES_PER_BLOCK)  // 171

// --- Kernel 0: zero the 288-float accumulator in workspace (poisoned 0xAA) ---
__global__ void pil_zero_ws(float* __restrict__ ws) {
    int i = threadIdx.x;
    if (i < BB * 9) ws[i] = 0.0f;
}

// --- Kernel 1: accumulate sum_n |est[b,n,i] - tgt[b,n,j]| into ws[b*9+i*3+j] ---
// Global loads are lane-contiguous (fully-coalesced 1KB/wave-load) into LDS;
// each lane then reads its 12-float chunk (4 complete S=3 groups) from LDS.
__global__ __launch_bounds__(THREADS, 6) void pil_partial(
        const float* __restrict__ est,
        const float* __restrict__ tgt,
        float* __restrict__ ws) {
    const int b   = blockIdx.x / BLOCKS_PER_B;
    const int blk = blockIdx.x % BLOCKS_PER_B;
    const int tid = threadIdx.x;

    const float4* eb = (const float4*)est + (size_t)b * F4_PER_B;
    const float4* tb = (const float4*)tgt + (size_t)b * F4_PER_B;

    __shared__ float4 se[TILE_F4];
    __shared__ float4 st[TILE_F4];

    float acc[9];
#pragma unroll
    for (int k = 0; k < 9; ++k) acc[k] = 0.0f;

    for (int k = 0; k < TILES_PER_BLOCK; ++k) {
        const int base = (blk * TILES_PER_BLOCK + k) * TILE_F4;
        // Coalesced global loads into registers (issued before the barrier so
        // their latency overlaps the previous tile's compute).
        const float4 e0 = eb[base + tid];
        const float4 e1 = eb[base + THREADS + tid];
        const float4 e2 = eb[base + 2 * THREADS + tid];
        const float4 t0 = tb[base + tid];
        const float4 t1 = tb[base + THREADS + tid];
        const float4 t2 = tb[base + 2 * THREADS + tid];

        if (k) __syncthreads();  // previous tile's compute reads must finish
        se[tid] = e0; se[THREADS + tid] = e1; se[2 * THREADS + tid] = e2;
        st[tid] = t0; st[THREADS + tid] = t1; st[2 * THREADS + tid] = t2;
        __syncthreads();

        // Each lane's 12 contiguous floats = 4 complete (i=0..2) groups.
        const float4* ep = (const float4*)((const float*)se + tid * 12);
        const float4* tp = (const float4*)((const float*)st + tid * 12);
        const float4 a0 = ep[0], a1 = ep[1], a2 = ep[2];
        const float4 b0 = tp[0], b1 = tp[1], b2 = tp[2];
        const float e[12] = {a0.x, a0.y, a0.z, a0.w, a1.x, a1.y,
                             a1.z, a1.w, a2.x, a2.y, a2.z, a2.w};
        const float t[12] = {b0.x, b0.y, b0.z, b0.w, b1.x, b1.y,
                             b1.z, b1.w, b2.x, b2.y, b2.z, b2.w};
#pragma unroll
        for (int g = 0; g < 4; ++g) {
#pragma unroll
            for (int i = 0; i < 3; ++i) {
#pragma unroll
                for (int j = 0; j < 3; ++j) {
                    acc[i * 3 + j] += fabsf(e[3 * g + i] - t[3 * g + j]);
                }
            }
        }
    }

    // Wave-level reduction (64 lanes) of each of the 9 accumulators.
#pragma unroll
    for (int k = 0; k < 9; ++k) {
        float v = acc[k];
#pragma unroll
        for (int off = 32; off > 0; off >>= 1) v += __shfl_down(v, off);
        acc[k] = v;
    }

    __shared__ float sred[2][9];
    const int wave = tid >> 6;
    const int lane = tid & 63;
    if (lane == 0) {
#pragma unroll
        for (int k = 0; k < 9; ++k) sred[wave][k] = acc[k];
    }
    __syncthreads();
    if (tid < 9) atomicAdd(&ws[b * 9 + tid], sred[0][tid] + sred[1][tid]);
}

// --- Kernel 2: per-b permutation losses, min over perms, mean over b ---
__global__ void pil_finalize(const float* __restrict__ ws, float* __restrict__ out) {
    const int lane = threadIdx.x;  // 64 threads, lanes >= BB idle
    float loss = 0.0f;
    if (lane < BB) {
        float C[3][3];
#pragma unroll
        for (int i = 0; i < 3; ++i)
#pragma unroll
            for (int j = 0; j < 3; ++j)
                C[i][j] = ws[lane * 9 + i * 3 + j] * (1.0f / (float)NN);

        const int P[6][3] = {{0, 1, 2}, {0, 2, 1}, {1, 0, 2},
                             {1, 2, 0}, {2, 0, 1}, {2, 1, 0}};
        float best = 3.4e38f;
#pragma unroll
        for (int p = 0; p < 6; ++p) {
            float l = (C[P[p][0]][0] + C[P[p][1]][1] + C[P[p][2]][2]) * (1.0f / 3.0f);
            best = fminf(best, l);
        }
        loss = best;
    }
#pragma unroll
    for (int off = 32; off > 0; off >>= 1) loss += __shfl_down(loss, off);
    if (lane == 0) out[0] = loss * (1.0f / (float)BB);
}

extern "C" void kernel_launch(void* const* d_in, const int* in_sizes, int n_in,
                              void* d_out, int out_size, void* d_ws, size_t ws_size,
                              hipStream_t stream) {
    const float* est = (const float*)d_in[0];
    const float* tgt = (const float*)d_in[1];
    float* ws  = (float*)d_ws;
    float* out = (float*)d_out;

    pil_zero_ws<<<1, 320, 0, stream>>>(ws);
    pil_partial<<<BB * BLOCKS_PER_B, THREADS, 0, stream>>>(est, tgt, ws);
    pil_finalize<<<1, 64, 0, stream>>>(ws, out);
}